// Round 3
// baseline (5907.656 us; speedup 1.0000x reference)
//
#include <hip/hip_runtime.h>
#include <math.h>

#define T_STEPS 168
#define INP     19
#define HID     64
#define ROWS    16
#define NTH     512
#define ZST     258

__device__ __forceinline__ float fast_sigmoid(float x) {
    return __builtin_amdgcn_rcpf(1.0f + __expf(-x));
}
__device__ __forceinline__ float fast_tanh(float x) {
    return 1.0f - 2.0f * __builtin_amdgcn_rcpf(1.0f + __expf(2.0f * x));
}

// 512 threads: A = tid 0..255 (layer1, 1 gate row, 84 w-regs),
//              B = tid 256..511 (layer2, 2 gate rows x half-K, 128 w-regs).
// Software skew: at iter t, A does layer1(t), B does layer2(t-1).
__global__ __launch_bounds__(NTH)
void lstm2_pipe_kernel(const float* __restrict__ x,
                       const float* __restrict__ Wih0, const float* __restrict__ Whh0,
                       const float* __restrict__ bih0, const float* __restrict__ bhh0,
                       const float* __restrict__ Wih1, const float* __restrict__ Whh1,
                       const float* __restrict__ bih1, const float* __restrict__ bhh1,
                       const float* __restrict__ Wfc,  const float* __restrict__ bfc,
                       float* __restrict__ out)
{
    __shared__ float xs [ROWS][20];       // x(t) tile, col 19 stays 0
    __shared__ float h1s[ROWS][HID];      // h1 state (single buffer)
    __shared__ float h2s[ROWS][HID];      // h2 state
    __shared__ float zs1[ROWS][ZST];      // layer1 pre-activations
    __shared__ float zs2[2][ROWS][ZST];   // layer2 partials (2 K-halves)

    const int tid = threadIdx.x;
    const int b0  = blockIdx.x * ROWS;
    const bool isA = (tid < 256);

    // ---- weights in registers: single constant-indexed array -> SROA ----
    float w[128];
    int gj = 0, half = 0;
    if (isA) {
        gj = tid;
        const float* p = Wih0 + gj * INP;
#pragma unroll
        for (int i = 0; i < INP; ++i) w[i] = p[i];
        w[19] = 0.0f;                       // pairs with zero xs[.][19]
        const float4* q = (const float4*)(Whh0 + gj * HID);
#pragma unroll
        for (int k = 0; k < 16; ++k) {
            float4 v = q[k];
            w[20+4*k+0] = v.x; w[20+4*k+1] = v.y;
            w[20+4*k+2] = v.z; w[20+4*k+3] = v.w;
        }
    } else {
        const int b = tid - 256;
        gj = b & 127; half = b >> 7;        // half0: Wih1 (h1 part), half1: Whh1 (h2 part)
        const float* Wb = half ? Whh1 : Wih1;
        const float4* q0 = (const float4*)(Wb + gj * HID);
        const float4* q1 = (const float4*)(Wb + (gj + 128) * HID);
#pragma unroll
        for (int k = 0; k < 16; ++k) {
            float4 v = q0[k];
            w[4*k+0] = v.x; w[4*k+1] = v.y; w[4*k+2] = v.z; w[4*k+3] = v.w;
            float4 u = q1[k];
            w[64+4*k+0] = u.x; w[64+4*k+1] = u.y; w[64+4*k+2] = u.z; w[64+4*k+3] = u.w;
        }
    }

    // ---- update-role: thread handles unit uu for rows rb..rb+3 of its layer ----
    const int ub = isA ? tid : (tid - 256);
    const int uu = ub >> 2;
    const int rb = (ub & 3) * 4;
    float bz[4];
    {
        const float* bi = isA ? bih0 : bih1;
        const float* bh = isA ? bhh0 : bhh1;
#pragma unroll
        for (int gi = 0; gi < 4; ++gi)
            bz[gi] = bi[uu + 64*gi] + bh[uu + 64*gi];
    }
    float cst[4] = {0.f, 0.f, 0.f, 0.f};

    // ---- staging thread constants (tid<304 stages one x element/iter) ----
    const int  srr = tid / INP;
    const int  sii = tid - srr * INP;
    const float* xsrc = x + ((size_t)(b0 + srr) * T_STEPS) * INP + sii;

    // ---- init LDS state ----
    for (int e = tid; e < ROWS * HID; e += NTH) {
        ((float*)h1s)[e] = 0.0f;
        ((float*)h2s)[e] = 0.0f;
        if (e < ROWS * 20) ((float*)xs)[e] = 0.0f;
    }
    __syncthreads();
    if (tid < ROWS * INP) xs[srr][sii] = xsrc[0];   // stage x(0)
    __syncthreads();

    for (int t = 0; t <= T_STEPS; ++t) {
        // ================= Z phase =================
        if (isA) {
            if (t < T_STEPS) {
                for (int r = 0; r < ROWS; ++r) {
                    const float4* xp = (const float4*)(&xs[r][0]);
                    const float4* hp = (const float4*)(&h1s[r][0]);
                    float a[4] = {0.f, 0.f, 0.f, 0.f};
#pragma unroll
                    for (int k = 0; k < 5; ++k) {        // x part (19 + 1 zero pad)
                        float4 v = xp[k];
                        a[k&3] = fmaf(v.x, w[4*k+0], a[k&3]);
                        a[k&3] = fmaf(v.y, w[4*k+1], a[k&3]);
                        a[k&3] = fmaf(v.z, w[4*k+2], a[k&3]);
                        a[k&3] = fmaf(v.w, w[4*k+3], a[k&3]);
                    }
#pragma unroll
                    for (int k = 0; k < 16; ++k) {       // h1(t-1) part
                        float4 v = hp[k];
                        a[k&3] = fmaf(v.x, w[20+4*k+0], a[k&3]);
                        a[k&3] = fmaf(v.y, w[20+4*k+1], a[k&3]);
                        a[k&3] = fmaf(v.z, w[20+4*k+2], a[k&3]);
                        a[k&3] = fmaf(v.w, w[20+4*k+3], a[k&3]);
                    }
                    zs1[r][gj] = (a[0] + a[1]) + (a[2] + a[3]);
                }
            }
        } else {
            if (t >= 1) {
                const float* src = half ? &h2s[0][0] : &h1s[0][0];
                for (int r = 0; r < ROWS; ++r) {
                    const float4* hp = (const float4*)(src + r * HID);
                    float a0 = 0.f, a1 = 0.f, c0 = 0.f, c1 = 0.f;
#pragma unroll
                    for (int k = 0; k < 16; ++k) {
                        float4 v = hp[k];
                        if (k & 1) {
                            a1 = fmaf(v.x, w[4*k+0], a1);
                            a1 = fmaf(v.y, w[4*k+1], a1);
                            a1 = fmaf(v.z, w[4*k+2], a1);
                            a1 = fmaf(v.w, w[4*k+3], a1);
                            c1 = fmaf(v.x, w[64+4*k+0], c1);
                            c1 = fmaf(v.y, w[64+4*k+1], c1);
                            c1 = fmaf(v.z, w[64+4*k+2], c1);
                            c1 = fmaf(v.w, w[64+4*k+3], c1);
                        } else {
                            a0 = fmaf(v.x, w[4*k+0], a0);
                            a0 = fmaf(v.y, w[4*k+1], a0);
                            a0 = fmaf(v.z, w[4*k+2], a0);
                            a0 = fmaf(v.w, w[4*k+3], a0);
                            c0 = fmaf(v.x, w[64+4*k+0], c0);
                            c0 = fmaf(v.y, w[64+4*k+1], c0);
                            c0 = fmaf(v.z, w[64+4*k+2], c0);
                            c0 = fmaf(v.w, w[64+4*k+3], c0);
                        }
                    }
                    zs2[half][r][gj]       = a0 + a1;
                    zs2[half][r][gj + 128] = c0 + c1;
                }
            }
        }
        __syncthreads();   // alpha: z buffers visible; all h/x reads of this iter done

        // ================= U phase =================
        if (isA) {
            if (t < T_STEPS) {
#pragma unroll
                for (int q4 = 0; q4 < 4; ++q4) {
                    const int r = rb + q4;
                    const float zi = zs1[r][uu      ] + bz[0];
                    const float zf = zs1[r][uu +  64] + bz[1];
                    const float zg = zs1[r][uu + 128] + bz[2];
                    const float zo = zs1[r][uu + 192] + bz[3];
                    const float ig = fast_sigmoid(zi);
                    const float fg = fast_sigmoid(zf);
                    const float gg = fast_tanh(zg);
                    const float og = fast_sigmoid(zo);
                    cst[q4] = fg * cst[q4] + ig * gg;
                    h1s[r][uu] = og * fast_tanh(cst[q4]);   // h1(t)
                }
            }
        } else {
            if (t >= 1) {
#pragma unroll
                for (int q4 = 0; q4 < 4; ++q4) {
                    const int r = rb + q4;
                    const float zi = zs2[0][r][uu      ] + zs2[1][r][uu      ] + bz[0];
                    const float zf = zs2[0][r][uu +  64] + zs2[1][r][uu +  64] + bz[1];
                    const float zg = zs2[0][r][uu + 128] + zs2[1][r][uu + 128] + bz[2];
                    const float zo = zs2[0][r][uu + 192] + zs2[1][r][uu + 192] + bz[3];
                    const float ig = fast_sigmoid(zi);
                    const float fg = fast_sigmoid(zf);
                    const float gg = fast_tanh(zg);
                    const float og = fast_sigmoid(zo);
                    cst[q4] = fg * cst[q4] + ig * gg;
                    h2s[r][uu] = og * fast_tanh(cst[q4]);   // h2(t-1)
                }
            }
        }
        // stage x(t+1) into xs (consumed next iter after beta)
        if (t + 1 < T_STEPS && tid < ROWS * INP)
            xs[srr][sii] = xsrc[(size_t)(t + 1) * INP];
        __syncthreads();   // beta: h/x updates visible for next Z phase
    }

    // ---- FC epilogue: out[b] = h2(T-1)[b,:] . Wfc + bfc ----
    if (tid < ROWS) {
        float a = bfc[0];
#pragma unroll
        for (int k = 0; k < HID; ++k)
            a = fmaf(h2s[tid][k], Wfc[k], a);
        out[b0 + tid] = a;
    }
}

extern "C" void kernel_launch(void* const* d_in, const int* in_sizes, int n_in,
                              void* d_out, int out_size, void* d_ws, size_t ws_size,
                              hipStream_t stream) {
    const float* x    = (const float*)d_in[0];
    const float* Wih0 = (const float*)d_in[1];
    const float* Whh0 = (const float*)d_in[2];
    const float* bih0 = (const float*)d_in[3];
    const float* bhh0 = (const float*)d_in[4];
    const float* Wih1 = (const float*)d_in[5];
    const float* Whh1 = (const float*)d_in[6];
    const float* bih1 = (const float*)d_in[7];
    const float* bhh1 = (const float*)d_in[8];
    const float* Wfc  = (const float*)d_in[9];
    const float* bfc  = (const float*)d_in[10];
    float* out = (float*)d_out;

    const int B = in_sizes[0] / (T_STEPS * INP);   // 4096
    const int grid = B / ROWS;                     // 256 workgroups, ~1 per CU

    lstm2_pipe_kernel<<<dim3(grid), dim3(NTH), 0, stream>>>(
        x, Wih0, Whh0, bih0, bhh0, Wih1, Whh1, bih1, bhh1, Wfc, bfc, out);
}

// Round 4
// 5857.219 us; speedup vs baseline: 1.0086x; 1.0086x over previous
//
#include <hip/hip_runtime.h>
#include <math.h>

#define T_STEPS 168
#define INP     19
#define HID     64
#define ROWS    16
#define NTH     512
#define ZST     258

__device__ __forceinline__ float fast_sigmoid(float x) {
    return __builtin_amdgcn_rcpf(1.0f + __expf(-x));
}
__device__ __forceinline__ float fast_tanh(float x) {
    return 1.0f - 2.0f * __builtin_amdgcn_rcpf(1.0f + __expf(2.0f * x));
}

// 512 threads: A = tid 0..255 (layer1, 1 gate row, 84 w-regs),
//              B = tid 256..511 (layer2, 2 gate rows x half-K, 128 w-regs).
// Software skew: at iter t, A does layer1(t), B does layer2(t-1).
// __launch_bounds__(512, 2): 2 waves/EU -> 256-VGPR budget, 1 block/CU.
// (Round 3 lesson: default heuristic capped at 128 VGPR -> 6 GB spill traffic.)
__global__ __launch_bounds__(NTH, 2)
void lstm2_pipe_kernel(const float* __restrict__ x,
                       const float* __restrict__ Wih0, const float* __restrict__ Whh0,
                       const float* __restrict__ bih0, const float* __restrict__ bhh0,
                       const float* __restrict__ Wih1, const float* __restrict__ Whh1,
                       const float* __restrict__ bih1, const float* __restrict__ bhh1,
                       const float* __restrict__ Wfc,  const float* __restrict__ bfc,
                       float* __restrict__ out)
{
    __shared__ float xs [ROWS][20];       // x(t) tile, col 19 stays 0
    __shared__ float h1s[ROWS][HID];      // h1 state (single buffer)
    __shared__ float h2s[ROWS][HID];      // h2 state
    __shared__ float zs1[ROWS][ZST];      // layer1 pre-activations
    __shared__ float zs2[2][ROWS][ZST];   // layer2 partials (2 K-halves)

    const int tid = threadIdx.x;
    const int b0  = blockIdx.x * ROWS;
    const bool isA = (tid < 256);

    // ---- weights in registers: single constant-indexed array -> SROA ----
    float w[128];
    int gj = 0, half = 0;
    if (isA) {
        gj = tid;
        const float* p = Wih0 + gj * INP;
#pragma unroll
        for (int i = 0; i < INP; ++i) w[i] = p[i];
        w[19] = 0.0f;                       // pairs with zero xs[.][19]
        const float4* q = (const float4*)(Whh0 + gj * HID);
#pragma unroll
        for (int k = 0; k < 16; ++k) {
            float4 v = q[k];
            w[20+4*k+0] = v.x; w[20+4*k+1] = v.y;
            w[20+4*k+2] = v.z; w[20+4*k+3] = v.w;
        }
    } else {
        const int b = tid - 256;
        gj = b & 127; half = b >> 7;        // half0: Wih1 (h1 part), half1: Whh1 (h2 part)
        const float* Wb = half ? Whh1 : Wih1;
        const float4* q0 = (const float4*)(Wb + gj * HID);
        const float4* q1 = (const float4*)(Wb + (gj + 128) * HID);
#pragma unroll
        for (int k = 0; k < 16; ++k) {
            float4 v = q0[k];
            w[4*k+0] = v.x; w[4*k+1] = v.y; w[4*k+2] = v.z; w[4*k+3] = v.w;
            float4 u = q1[k];
            w[64+4*k+0] = u.x; w[64+4*k+1] = u.y; w[64+4*k+2] = u.z; w[64+4*k+3] = u.w;
        }
    }

    // ---- update-role: thread handles unit uu for rows rb..rb+3 of its layer ----
    const int ub = isA ? tid : (tid - 256);
    const int uu = ub >> 2;
    const int rb = (ub & 3) * 4;
    float bz[4];
    {
        const float* bi = isA ? bih0 : bih1;
        const float* bh = isA ? bhh0 : bhh1;
#pragma unroll
        for (int gi = 0; gi < 4; ++gi)
            bz[gi] = bi[uu + 64*gi] + bh[uu + 64*gi];
    }
    float cst[4] = {0.f, 0.f, 0.f, 0.f};

    // ---- staging thread constants (tid<304 stages one x element/iter) ----
    const int  srr = tid / INP;
    const int  sii = tid - srr * INP;
    const float* xsrc = x + ((size_t)(b0 + srr) * T_STEPS) * INP + sii;

    // ---- init LDS state ----
    for (int e = tid; e < ROWS * HID; e += NTH) {
        ((float*)h1s)[e] = 0.0f;
        ((float*)h2s)[e] = 0.0f;
        if (e < ROWS * 20) ((float*)xs)[e] = 0.0f;
    }
    __syncthreads();
    if (tid < ROWS * INP) xs[srr][sii] = xsrc[0];   // stage x(0)
    __syncthreads();

    for (int t = 0; t <= T_STEPS; ++t) {
        // ================= Z phase =================
        if (isA) {
            if (t < T_STEPS) {
                for (int r = 0; r < ROWS; ++r) {
                    const float4* xp = (const float4*)(&xs[r][0]);
                    const float4* hp = (const float4*)(&h1s[r][0]);
                    float a[4] = {0.f, 0.f, 0.f, 0.f};
#pragma unroll
                    for (int k = 0; k < 5; ++k) {        // x part (19 + 1 zero pad)
                        float4 v = xp[k];
                        a[k&3] = fmaf(v.x, w[4*k+0], a[k&3]);
                        a[k&3] = fmaf(v.y, w[4*k+1], a[k&3]);
                        a[k&3] = fmaf(v.z, w[4*k+2], a[k&3]);
                        a[k&3] = fmaf(v.w, w[4*k+3], a[k&3]);
                    }
#pragma unroll
                    for (int k = 0; k < 16; ++k) {       // h1(t-1) part
                        float4 v = hp[k];
                        a[k&3] = fmaf(v.x, w[20+4*k+0], a[k&3]);
                        a[k&3] = fmaf(v.y, w[20+4*k+1], a[k&3]);
                        a[k&3] = fmaf(v.z, w[20+4*k+2], a[k&3]);
                        a[k&3] = fmaf(v.w, w[20+4*k+3], a[k&3]);
                    }
                    zs1[r][gj] = (a[0] + a[1]) + (a[2] + a[3]);
                }
            }
        } else {
            if (t >= 1) {
                const float* src = half ? &h2s[0][0] : &h1s[0][0];
                for (int r = 0; r < ROWS; ++r) {
                    const float4* hp = (const float4*)(src + r * HID);
                    float a0 = 0.f, a1 = 0.f, c0 = 0.f, c1 = 0.f;
#pragma unroll
                    for (int k = 0; k < 16; ++k) {
                        float4 v = hp[k];
                        if (k & 1) {
                            a1 = fmaf(v.x, w[4*k+0], a1);
                            a1 = fmaf(v.y, w[4*k+1], a1);
                            a1 = fmaf(v.z, w[4*k+2], a1);
                            a1 = fmaf(v.w, w[4*k+3], a1);
                            c1 = fmaf(v.x, w[64+4*k+0], c1);
                            c1 = fmaf(v.y, w[64+4*k+1], c1);
                            c1 = fmaf(v.z, w[64+4*k+2], c1);
                            c1 = fmaf(v.w, w[64+4*k+3], c1);
                        } else {
                            a0 = fmaf(v.x, w[4*k+0], a0);
                            a0 = fmaf(v.y, w[4*k+1], a0);
                            a0 = fmaf(v.z, w[4*k+2], a0);
                            a0 = fmaf(v.w, w[4*k+3], a0);
                            c0 = fmaf(v.x, w[64+4*k+0], c0);
                            c0 = fmaf(v.y, w[64+4*k+1], c0);
                            c0 = fmaf(v.z, w[64+4*k+2], c0);
                            c0 = fmaf(v.w, w[64+4*k+3], c0);
                        }
                    }
                    zs2[half][r][gj]       = a0 + a1;
                    zs2[half][r][gj + 128] = c0 + c1;
                }
            }
        }
        __syncthreads();   // alpha: z buffers visible; all h/x reads of this iter done

        // ================= U phase =================
        if (isA) {
            if (t < T_STEPS) {
#pragma unroll
                for (int q4 = 0; q4 < 4; ++q4) {
                    const int r = rb + q4;
                    const float zi = zs1[r][uu      ] + bz[0];
                    const float zf = zs1[r][uu +  64] + bz[1];
                    const float zg = zs1[r][uu + 128] + bz[2];
                    const float zo = zs1[r][uu + 192] + bz[3];
                    const float ig = fast_sigmoid(zi);
                    const float fg = fast_sigmoid(zf);
                    const float gg = fast_tanh(zg);
                    const float og = fast_sigmoid(zo);
                    cst[q4] = fg * cst[q4] + ig * gg;
                    h1s[r][uu] = og * fast_tanh(cst[q4]);   // h1(t)
                }
            }
        } else {
            if (t >= 1) {
#pragma unroll
                for (int q4 = 0; q4 < 4; ++q4) {
                    const int r = rb + q4;
                    const float zi = zs2[0][r][uu      ] + zs2[1][r][uu      ] + bz[0];
                    const float zf = zs2[0][r][uu +  64] + zs2[1][r][uu +  64] + bz[1];
                    const float zg = zs2[0][r][uu + 128] + zs2[1][r][uu + 128] + bz[2];
                    const float zo = zs2[0][r][uu + 192] + zs2[1][r][uu + 192] + bz[3];
                    const float ig = fast_sigmoid(zi);
                    const float fg = fast_sigmoid(zf);
                    const float gg = fast_tanh(zg);
                    const float og = fast_sigmoid(zo);
                    cst[q4] = fg * cst[q4] + ig * gg;
                    h2s[r][uu] = og * fast_tanh(cst[q4]);   // h2(t-1)
                }
            }
        }
        // stage x(t+1) into xs (consumed next iter after beta)
        if (t + 1 < T_STEPS && tid < ROWS * INP)
            xs[srr][sii] = xsrc[(size_t)(t + 1) * INP];
        __syncthreads();   // beta: h/x updates visible for next Z phase
    }

    // ---- FC epilogue: out[b] = h2(T-1)[b,:] . Wfc + bfc ----
    if (tid < ROWS) {
        float a = bfc[0];
#pragma unroll
        for (int k = 0; k < HID; ++k)
            a = fmaf(h2s[tid][k], Wfc[k], a);
        out[b0 + tid] = a;
    }
}

extern "C" void kernel_launch(void* const* d_in, const int* in_sizes, int n_in,
                              void* d_out, int out_size, void* d_ws, size_t ws_size,
                              hipStream_t stream) {
    const float* x    = (const float*)d_in[0];
    const float* Wih0 = (const float*)d_in[1];
    const float* Whh0 = (const float*)d_in[2];
    const float* bih0 = (const float*)d_in[3];
    const float* bhh0 = (const float*)d_in[4];
    const float* Wih1 = (const float*)d_in[5];
    const float* Whh1 = (const float*)d_in[6];
    const float* bih1 = (const float*)d_in[7];
    const float* bhh1 = (const float*)d_in[8];
    const float* Wfc  = (const float*)d_in[9];
    const float* bfc  = (const float*)d_in[10];
    float* out = (float*)d_out;

    const int B = in_sizes[0] / (T_STEPS * INP);   // 4096
    const int grid = B / ROWS;                     // 256 workgroups, 1 per CU

    lstm2_pipe_kernel<<<dim3(grid), dim3(NTH), 0, stream>>>(
        x, Wih0, Whh0, bih0, bhh0, Wih1, Whh1, bih1, bhh1, Wfc, bfc, out);
}

// Round 5
// 5346.548 us; speedup vs baseline: 1.1049x; 1.0955x over previous
//
#include <hip/hip_runtime.h>
#include <math.h>

#define T_STEPS 168
#define INP     19
#define HID     64
#define ROWS    16
#define NTH     1024
#define ZST     258
#define HST     68

__device__ __forceinline__ float fast_sigmoid(float x) {
    return __builtin_amdgcn_rcpf(1.0f + __expf(-x));
}
__device__ __forceinline__ float fast_tanh(float x) {
    return 1.0f - 2.0f * __builtin_amdgcn_rcpf(1.0f + __expf(2.0f * x));
}

// 1024 threads, every thread holds <=64 weight floats (fits the allocator's
// preferred 128-VGPR/4-wave point -- rounds 2-4 showed ~160-reg designs spill).
//   tid 0..511   : layer1, gate row g = tid&255, K-half = tid>>8
//                  half0: x(20 incl pad) + h1[0:24)  (44 w-regs)
//                  half1: h1[24:64)                  (40 w-regs)
//   tid 512..1023: layer2, gate row g, half0: Wih1 row / half1: Whh1 row (64 regs)
// Software skew: at iter t, layer1 computes step t, layer2 computes step t-1.
__global__ __launch_bounds__(NTH, 4)
void lstm2_pipe2_kernel(const float* __restrict__ x,
                        const float* __restrict__ Wih0, const float* __restrict__ Whh0,
                        const float* __restrict__ bih0, const float* __restrict__ bhh0,
                        const float* __restrict__ Wih1, const float* __restrict__ Whh1,
                        const float* __restrict__ bih1, const float* __restrict__ bhh1,
                        const float* __restrict__ Wfc,  const float* __restrict__ bfc,
                        float* __restrict__ out)
{
    __shared__ float xs [ROWS][20];            // x(t) tile, col 19 stays 0
    __shared__ float h1s[ROWS][HST];           // stride 68: h-writes land 2-way max
    __shared__ float h2s[ROWS][HST];
    __shared__ float zp [2][2][ROWS][ZST];     // z partials [layer][K-half][row][gate]

    const int tid  = threadIdx.x;
    const int b0   = blockIdx.x * ROWS;
    const int lay  = tid >> 9;                 // 0: layer1, 1: layer2
    const int lt   = tid & 511;
    const int g    = lt & 255;                 // gate row
    const int half = lt >> 8;                  // K-half

    // ---- weights into registers (<=64 floats, constant-indexed -> SROA) ----
    float w[64];
#pragma unroll
    for (int i = 0; i < 64; ++i) w[i] = 0.0f;

    if (lay == 0) {
        if (half == 0) {
            const float* p = Wih0 + g * INP;
#pragma unroll
            for (int i = 0; i < INP; ++i) w[i] = p[i];   // w[19] stays 0 (pads xs col 19)
            const float4* q = (const float4*)(Whh0 + g * HID);
#pragma unroll
            for (int k = 0; k < 6; ++k) {                // h1[0:24)
                float4 v = q[k];
                w[20+4*k+0] = v.x; w[20+4*k+1] = v.y;
                w[20+4*k+2] = v.z; w[20+4*k+3] = v.w;
            }
        } else {
            const float4* q = (const float4*)(Whh0 + g * HID);
#pragma unroll
            for (int k = 0; k < 10; ++k) {               // h1[24:64)
                float4 v = q[6 + k];
                w[4*k+0] = v.x; w[4*k+1] = v.y; w[4*k+2] = v.z; w[4*k+3] = v.w;
            }
        }
    } else {
        const float* Wb = half ? Whh1 : Wih1;
        const float4* q = (const float4*)(Wb + g * HID);
#pragma unroll
        for (int k = 0; k < 16; ++k) {
            float4 v = q[k];
            w[4*k+0] = v.x; w[4*k+1] = v.y; w[4*k+2] = v.z; w[4*k+3] = v.w;
        }
    }

    // ---- update role: unit uu, rows rp..rp+1 of my layer ----
    const int uu = lt >> 3;                    // 0..63
    const int rp = (lt & 7) * 2;               // 0,2,...,14
    float bz[4];
    {
        const float* bi = lay ? bih1 : bih0;
        const float* bh = lay ? bhh1 : bhh0;
#pragma unroll
        for (int gi = 0; gi < 4; ++gi)
            bz[gi] = bi[uu + 64*gi] + bh[uu + 64*gi];
    }
    float cst[2] = {0.f, 0.f};

    // ---- x staging constants (tid<304 stages one element/iter) ----
    const int  srr = tid / INP;
    const int  sii = tid - srr * INP;
    const float* xsrc = x + ((size_t)(b0 + srr) * T_STEPS) * INP + sii;

    // ---- init LDS state ----
    for (int e = tid; e < ROWS * HST; e += NTH) {
        ((float*)h1s)[e] = 0.0f;
        ((float*)h2s)[e] = 0.0f;
    }
    if (tid < ROWS * 20) ((float*)xs)[tid] = 0.0f;
    __syncthreads();
    if (tid < ROWS * INP) xs[srr][sii] = xsrc[0];       // stage x(0)
    __syncthreads();

    for (int t = 0; t <= T_STEPS; ++t) {
        // ================= Z phase =================
        if (lay == 0) {
            if (t < T_STEPS) {
                if (half == 0) {
                    for (int r = 0; r < ROWS; ++r) {
                        const float4* xp = (const float4*)(&xs[r][0]);
                        const float4* hp = (const float4*)(&h1s[r][0]);
                        float a[4] = {0.f, 0.f, 0.f, 0.f};
#pragma unroll
                        for (int k = 0; k < 5; ++k) {            // x part
                            float4 v = xp[k];
                            a[k&3] = fmaf(v.x, w[4*k+0], a[k&3]);
                            a[k&3] = fmaf(v.y, w[4*k+1], a[k&3]);
                            a[k&3] = fmaf(v.z, w[4*k+2], a[k&3]);
                            a[k&3] = fmaf(v.w, w[4*k+3], a[k&3]);
                        }
#pragma unroll
                        for (int k = 0; k < 6; ++k) {            // h1[0:24)
                            float4 v = hp[k];
                            a[(5+k)&3] = fmaf(v.x, w[20+4*k+0], a[(5+k)&3]);
                            a[(5+k)&3] = fmaf(v.y, w[20+4*k+1], a[(5+k)&3]);
                            a[(5+k)&3] = fmaf(v.z, w[20+4*k+2], a[(5+k)&3]);
                            a[(5+k)&3] = fmaf(v.w, w[20+4*k+3], a[(5+k)&3]);
                        }
                        zp[0][0][r][g] = (a[0] + a[1]) + (a[2] + a[3]);
                    }
                } else {
                    for (int r = 0; r < ROWS; ++r) {
                        const float4* hp = (const float4*)(&h1s[r][24]);
                        float a[4] = {0.f, 0.f, 0.f, 0.f};
#pragma unroll
                        for (int k = 0; k < 10; ++k) {           // h1[24:64)
                            float4 v = hp[k];
                            a[k&3] = fmaf(v.x, w[4*k+0], a[k&3]);
                            a[k&3] = fmaf(v.y, w[4*k+1], a[k&3]);
                            a[k&3] = fmaf(v.z, w[4*k+2], a[k&3]);
                            a[k&3] = fmaf(v.w, w[4*k+3], a[k&3]);
                        }
                        zp[0][1][r][g] = (a[0] + a[1]) + (a[2] + a[3]);
                    }
                }
            }
        } else {
            if (t >= 1) {
                const float* src = half ? &h2s[0][0] : &h1s[0][0];
                for (int r = 0; r < ROWS; ++r) {
                    const float4* hp = (const float4*)(src + r * HST);
                    float a[4] = {0.f, 0.f, 0.f, 0.f};
#pragma unroll
                    for (int k = 0; k < 16; ++k) {
                        float4 v = hp[k];
                        a[k&3] = fmaf(v.x, w[4*k+0], a[k&3]);
                        a[k&3] = fmaf(v.y, w[4*k+1], a[k&3]);
                        a[k&3] = fmaf(v.z, w[4*k+2], a[k&3]);
                        a[k&3] = fmaf(v.w, w[4*k+3], a[k&3]);
                    }
                    zp[1][half][r][g] = (a[0] + a[1]) + (a[2] + a[3]);
                }
            }
        }
        __syncthreads();   // alpha: z partials visible; all h/x reads done

        // ================= U phase =================
        {
            const bool act = (lay == 0) ? (t < T_STEPS) : (t >= 1);
            if (act) {
#pragma unroll
                for (int j = 0; j < 2; ++j) {
                    const int r = rp + j;
                    const float zi = zp[lay][0][r][uu      ] + zp[lay][1][r][uu      ] + bz[0];
                    const float zf = zp[lay][0][r][uu +  64] + zp[lay][1][r][uu +  64] + bz[1];
                    const float zg = zp[lay][0][r][uu + 128] + zp[lay][1][r][uu + 128] + bz[2];
                    const float zo = zp[lay][0][r][uu + 192] + zp[lay][1][r][uu + 192] + bz[3];
                    const float ig = fast_sigmoid(zi);
                    const float fg = fast_sigmoid(zf);
                    const float gg = fast_tanh(zg);
                    const float og = fast_sigmoid(zo);
                    cst[j] = fg * cst[j] + ig * gg;
                    const float hv = og * fast_tanh(cst[j]);
                    if (lay == 0) h1s[r][uu] = hv;     // h1(t)
                    else          h2s[r][uu] = hv;     // h2(t-1)
                }
            }
        }
        // stage x(t+1) (consumed next iter after beta)
        if (t + 1 < T_STEPS && tid < ROWS * INP)
            xs[srr][sii] = xsrc[(size_t)(t + 1) * INP];
        __syncthreads();   // beta: h/x updates visible for next Z phase
    }

    // ---- FC epilogue: out[b] = h2(T-1)[b,:] . Wfc + bfc ----
    if (tid < ROWS) {
        float a = bfc[0];
#pragma unroll
        for (int k = 0; k < HID; ++k)
            a = fmaf(h2s[tid][k], Wfc[k], a);
        out[b0 + tid] = a;
    }
}

extern "C" void kernel_launch(void* const* d_in, const int* in_sizes, int n_in,
                              void* d_out, int out_size, void* d_ws, size_t ws_size,
                              hipStream_t stream) {
    const float* x    = (const float*)d_in[0];
    const float* Wih0 = (const float*)d_in[1];
    const float* Whh0 = (const float*)d_in[2];
    const float* bih0 = (const float*)d_in[3];
    const float* bhh0 = (const float*)d_in[4];
    const float* Wih1 = (const float*)d_in[5];
    const float* Whh1 = (const float*)d_in[6];
    const float* bih1 = (const float*)d_in[7];
    const float* bhh1 = (const float*)d_in[8];
    const float* Wfc  = (const float*)d_in[9];
    const float* bfc  = (const float*)d_in[10];
    float* out = (float*)d_out;

    const int B = in_sizes[0] / (T_STEPS * INP);   // 4096
    const int grid = B / ROWS;                     // 256 workgroups, 1 per CU

    lstm2_pipe2_kernel<<<dim3(grid), dim3(NTH), 0, stream>>>(
        x, Wih0, Whh0, bih0, bhh0, Wih1, Whh1, bih1, bhh1, Wfc, bfc, out);
}

// Round 6
// 330.745 us; speedup vs baseline: 17.8617x; 16.1652x over previous
//
#include <hip/hip_runtime.h>
#include <math.h>

#define T_STEPS 168
#define INP     19
#define HID     64
#define ROWS    16
#define NTH     1024
#define ZST     264   // z row stride (fp32 words)
#define HSTH    72    // h row stride (f16) -> 144 B, 16B-aligned, 2-way banks max
#define XSTH    40    // x row stride (f16) -> 80 B, 16B-aligned

typedef _Float16 half8  __attribute__((ext_vector_type(8)));
typedef float    floatx4 __attribute__((ext_vector_type(4)));

__device__ __forceinline__ float fast_sigmoid(float x) {
    return __builtin_amdgcn_rcpf(1.0f + __expf(-x));
}
__device__ __forceinline__ float fast_tanh(float x) {
    return 1.0f - 2.0f * __builtin_amdgcn_rcpf(1.0f + __expf(2.0f * x));
}

// MFMA LSTM: 16 waves/block. Waves 0-7: layer1(t) z-GEMM; waves 8-15: layer2(t-1).
// B-frags (weights, f16) live in VGPRs for the whole kernel (32 regs/lane).
// A-frags (h, f16) from LDS; C = z accumulated fp32 with bias pre-init.
// U-phase: thread=(layer, unit, 2 rows); cell state in registers.
// LDS padded >80 KB => 1 block/CU => allocator targets 4 waves/EU = 128 VGPR
// (rounds 3-5: allocator spills to hit whatever occupancy LDS permits).
__global__ __launch_bounds__(NTH) __attribute__((amdgpu_waves_per_eu(4, 4)))
void lstm2_mfma_kernel(const float* __restrict__ x,
                       const float* __restrict__ Wih0, const float* __restrict__ Whh0,
                       const float* __restrict__ bih0, const float* __restrict__ bhh0,
                       const float* __restrict__ Wih1, const float* __restrict__ Whh1,
                       const float* __restrict__ bih1, const float* __restrict__ bhh1,
                       const float* __restrict__ Wfc,  const float* __restrict__ bfc,
                       float* __restrict__ out)
{
    __shared__ __align__(16) _Float16 xf [ROWS][XSTH];   // x(t), k>=19 stays 0
    __shared__ __align__(16) _Float16 h1f[ROWS][HSTH];
    __shared__ __align__(16) _Float16 h2f[ROWS][HSTH];
    __shared__ float z1[ROWS][ZST];
    __shared__ float z2[ROWS][ZST];
    __shared__ float hout[ROWS][HID];                    // fp32 h2(T-1) for FC
    __shared__ float ldspad[10240];                      // occupancy clamp (40 KB)

    const int tid  = threadIdx.x;
    const int b0   = blockIdx.x * ROWS;
    const int wv   = tid >> 6;         // wave 0..15
    const int lane = tid & 63;
    const int quad = lane >> 4;
    const int l16  = lane & 15;
    const int wlay = wv >> 3;          // Z-role: 0=layer1, 1=layer2
    const int wl   = wv & 7;
    const int kq   = quad * 8;         // my k-offset inside a K-tile

    // ---- B-fragments (weights) + bias, loaded ONCE ----
    // layout (m120-verified): B[k][n]: n = lane&15, k = quad*8 + e (e contiguous)
    half8 bfr[2][4];
    float bzv[2];
#pragma unroll
    for (int j = 0; j < 2; ++j) {
        const int gate = wl * 32 + j * 16 + l16;
        if (wlay == 0) {
            const float* wr = Wih0 + gate * INP;
#pragma unroll
            for (int e = 0; e < 8; ++e) {
                const int k = kq + e;
                bfr[j][0][e] = (k < INP) ? (_Float16)wr[k] : (_Float16)0.0f;
            }
            const float* hr = Whh0 + gate * HID;
#pragma unroll
            for (int kt = 0; kt < 2; ++kt)
#pragma unroll
                for (int e = 0; e < 8; ++e)
                    bfr[j][1 + kt][e] = (_Float16)hr[kt * 32 + kq + e];
            bfr[j][3] = bfr[j][2];     // unused slot, keep defined
            bzv[j] = bih0[gate] + bhh0[gate];
        } else {
            const float* ir = Wih1 + gate * HID;
            const float* hr = Whh1 + gate * HID;
#pragma unroll
            for (int kt = 0; kt < 2; ++kt)
#pragma unroll
                for (int e = 0; e < 8; ++e) {
                    bfr[j][kt][e]     = (_Float16)ir[kt * 32 + kq + e];
                    bfr[j][2 + kt][e] = (_Float16)hr[kt * 32 + kq + e];
                }
            bzv[j] = bih1[gate] + bhh1[gate];
        }
    }

    // ---- U-role: layer ulay, unit uu, rows ur0/ur0+1; c-state in regs ----
    const int ulay = tid >> 9;
    const int uu   = tid & 63;
    const int ur0  = ((tid >> 6) & 7) * 2;
    float cst[2] = {0.f, 0.f};

    // ---- x staging constants (threads 512..815 stage one element/iter) ----
    const int st = tid - 512;
    int srr = 0, sii = 0;
    const float* xsrc = nullptr;
    if (st >= 0 && st < ROWS * INP) {
        srr = st / INP; sii = st - srr * INP;
        xsrc = x + ((size_t)(b0 + srr) * T_STEPS) * INP + sii;
    }

    // ---- init LDS ----
    for (int e = tid; e < ROWS * XSTH; e += NTH) ((_Float16*)xf)[e] = (_Float16)0.f;
    for (int e = tid; e < ROWS * HSTH; e += NTH) {
        ((_Float16*)h1f)[e] = (_Float16)0.f;
        ((_Float16*)h2f)[e] = (_Float16)0.f;
    }
    for (int e = tid; e < 10240; e += NTH) ldspad[e] = 0.f;
    __syncthreads();
    if (xsrc) xf[srr][sii] = (_Float16)xsrc[0];     // stage x(0)
    __syncthreads();

    for (int t = 0; t <= T_STEPS; ++t) {
        // ================= Z phase (MFMA) =================
        if (wlay == 0) {
            if (t < T_STEPS) {
                // A-frag (m120-verified): A[m=lane&15][k=quad*8+e]
                const half8 ax = *(const half8*)&xf [l16][kq];
                const half8 a0 = *(const half8*)&h1f[l16][kq];
                const half8 a1 = *(const half8*)&h1f[l16][32 + kq];
#pragma unroll
                for (int j = 0; j < 2; ++j) {
                    floatx4 acc = {bzv[j], bzv[j], bzv[j], bzv[j]};
                    acc = __builtin_amdgcn_mfma_f32_16x16x32_f16(ax, bfr[j][0], acc, 0, 0, 0);
                    acc = __builtin_amdgcn_mfma_f32_16x16x32_f16(a0, bfr[j][1], acc, 0, 0, 0);
                    acc = __builtin_amdgcn_mfma_f32_16x16x32_f16(a1, bfr[j][2], acc, 0, 0, 0);
                    const int gcol = wl * 32 + j * 16 + l16;
#pragma unroll
                    for (int rg = 0; rg < 4; ++rg)      // C/D: col=lane&15, row=quad*4+rg
                        z1[quad * 4 + rg][gcol] = acc[rg];
                }
            }
        } else {
            if (t >= 1) {
                const half8 p0 = *(const half8*)&h1f[l16][kq];
                const half8 p1 = *(const half8*)&h1f[l16][32 + kq];
                const half8 q0 = *(const half8*)&h2f[l16][kq];
                const half8 q1 = *(const half8*)&h2f[l16][32 + kq];
#pragma unroll
                for (int j = 0; j < 2; ++j) {
                    floatx4 acc = {bzv[j], bzv[j], bzv[j], bzv[j]};
                    acc = __builtin_amdgcn_mfma_f32_16x16x32_f16(p0, bfr[j][0], acc, 0, 0, 0);
                    acc = __builtin_amdgcn_mfma_f32_16x16x32_f16(p1, bfr[j][1], acc, 0, 0, 0);
                    acc = __builtin_amdgcn_mfma_f32_16x16x32_f16(q0, bfr[j][2], acc, 0, 0, 0);
                    acc = __builtin_amdgcn_mfma_f32_16x16x32_f16(q1, bfr[j][3], acc, 0, 0, 0);
                    const int gcol = wl * 32 + j * 16 + l16;
#pragma unroll
                    for (int rg = 0; rg < 4; ++rg)
                        z2[quad * 4 + rg][gcol] = acc[rg];
                }
            }
        }
        __syncthreads();   // alpha: z visible; all h/x reads of this iter done

        // ================= U phase =================
        if (ulay == 0) {
            if (t < T_STEPS) {
#pragma unroll
                for (int jj = 0; jj < 2; ++jj) {
                    const int r = ur0 + jj;
                    const float zi = z1[r][uu], zf = z1[r][uu + 64];
                    const float zg = z1[r][uu + 128], zo = z1[r][uu + 192];
                    const float ig = fast_sigmoid(zi), fg = fast_sigmoid(zf);
                    const float gg = fast_tanh(zg),   og = fast_sigmoid(zo);
                    cst[jj] = fg * cst[jj] + ig * gg;
                    h1f[r][uu] = (_Float16)(og * fast_tanh(cst[jj]));   // h1(t)
                }
            }
        } else {
            if (t >= 1) {
#pragma unroll
                for (int jj = 0; jj < 2; ++jj) {
                    const int r = ur0 + jj;
                    const float zi = z2[r][uu], zf = z2[r][uu + 64];
                    const float zg = z2[r][uu + 128], zo = z2[r][uu + 192];
                    const float ig = fast_sigmoid(zi), fg = fast_sigmoid(zf);
                    const float gg = fast_tanh(zg),   og = fast_sigmoid(zo);
                    cst[jj] = fg * cst[jj] + ig * gg;
                    const float hv = og * fast_tanh(cst[jj]);
                    h2f[r][uu] = (_Float16)hv;                          // h2(t-1)
                    if (t == T_STEPS) hout[r][uu] = hv;                 // fp32 for FC
                }
            }
            if (t + 1 < T_STEPS && st < ROWS * INP)
                xf[srr][sii] = (_Float16)xsrc[(size_t)(t + 1) * INP];   // stage x(t+1)
        }
        __syncthreads();   // beta: h/x updates visible for next Z phase
    }

    // ---- FC epilogue: out[b] = h2(T-1)[b,:] . Wfc + bfc ----
    if (tid < ROWS) {
        float a = bfc[0];
        const float* hr = hout[tid];
#pragma unroll
        for (int k = 0; k < HID; ++k)
            a = fmaf(hr[k], Wfc[k], a);
        out[b0 + tid] = a + ldspad[tid];   // ldspad==0; keeps the 40 KB pad live
    }
}

extern "C" void kernel_launch(void* const* d_in, const int* in_sizes, int n_in,
                              void* d_out, int out_size, void* d_ws, size_t ws_size,
                              hipStream_t stream) {
    const float* x    = (const float*)d_in[0];
    const float* Wih0 = (const float*)d_in[1];
    const float* Whh0 = (const float*)d_in[2];
    const float* bih0 = (const float*)d_in[3];
    const float* bhh0 = (const float*)d_in[4];
    const float* Wih1 = (const float*)d_in[5];
    const float* Whh1 = (const float*)d_in[6];
    const float* bih1 = (const float*)d_in[7];
    const float* bhh1 = (const float*)d_in[8];
    const float* Wfc  = (const float*)d_in[9];
    const float* bfc  = (const float*)d_in[10];
    float* out = (float*)d_out;

    const int B = in_sizes[0] / (T_STEPS * INP);   // 4096
    const int grid = B / ROWS;                     // 256 workgroups, 1 per CU

    lstm2_mfma_kernel<<<dim3(grid), dim3(NTH), 0, stream>>>(
        x, Wih0, Whh0, bih0, bhh0, Wih1, Whh1, bih1, bhh1, Wfc, bfc, out);
}

// Round 7
// 299.858 us; speedup vs baseline: 19.7015x; 1.1030x over previous
//
#include <hip/hip_runtime.h>
#include <math.h>

#define T_STEPS 168
#define INP     19
#define HID     64
#define ROWS    16
#define NTH     512
#define HSTH    72    // h row stride (f16): 144 B, 16B-aligned
#define XSTH    40    // x row stride (f16): 80 B

typedef _Float16 half8   __attribute__((ext_vector_type(8)));
typedef float    floatx4 __attribute__((ext_vector_type(4)));

__device__ __forceinline__ float fast_sigmoid(float x) {
    return __builtin_amdgcn_rcpf(1.0f + __expf(-x));
}
__device__ __forceinline__ float fast_tanh(float x) {
    return 1.0f - 2.0f * __builtin_amdgcn_rcpf(1.0f + __expf(2.0f * x));
}

// 8 waves: 0-3 layer1(t), 4-7 layer2(t-1). Wave (lay,uq) computes ALL 4 gate
// tiles for units uq*16..uq*16+15 -> lane (quad,l16) ends up holding the 4
// gate pre-activations of cell (row=quad*4+rg, u=uq*16+l16) directly in the
// MFMA C-layout. Activation + cell state stay in registers; no z round-trip.
// amdgpu_waves_per_eu(2,2): grid=256 gives 1 block/CU (2 waves/EU) anyway;
// this sets the allocator budget to 256 VGPR so the ~118-reg path never
// spills (rounds 2-5 lesson: allocator spills to chase occupancy).
__global__ __launch_bounds__(NTH) __attribute__((amdgpu_waves_per_eu(2, 2)))
void lstm2_mfma2_kernel(const float* __restrict__ x,
                        const float* __restrict__ Wih0, const float* __restrict__ Whh0,
                        const float* __restrict__ bih0, const float* __restrict__ bhh0,
                        const float* __restrict__ Wih1, const float* __restrict__ Whh1,
                        const float* __restrict__ bih1, const float* __restrict__ bhh1,
                        const float* __restrict__ Wfc,  const float* __restrict__ bfc,
                        float* __restrict__ out)
{
    __shared__ __align__(16) _Float16 xf [ROWS][XSTH];   // x(t), cols 19.. stay 0
    __shared__ __align__(16) _Float16 h1f[ROWS][HSTH];
    __shared__ __align__(16) _Float16 h2f[ROWS][HSTH];
    __shared__ float hout[ROWS][HID];                    // fp32 h2(T-1) for FC

    const int tid  = threadIdx.x;
    const int b0   = blockIdx.x * ROWS;
    const int wv   = tid >> 6;
    const int lane = tid & 63;
    const int quad = lane >> 4;
    const int l16  = lane & 15;
    const int kq   = quad * 8;         // k-offset inside a 32-wide K-tile
    const int lay  = wv >> 2;          // 0: layer1, 1: layer2
    const int uq   = wv & 3;           // unit quarter
    const int u    = uq * 16 + l16;    // my unit column

    // ---- B-fragments (weights, f16) + bias: loaded ONCE, live all kernel ----
    // B[k][n]: n = lane&15, k = quad*8 + e  (same mapping r6 validated)
    half8 bfr[4][4];
    float bz[4];
#pragma unroll
    for (int gi = 0; gi < 4; ++gi) {
        const int gr = gi * 64 + u;    // gate row in the 4H weight matrices
        if (lay == 0) {
            const float* wr = Wih0 + gr * INP;
#pragma unroll
            for (int e = 0; e < 8; ++e) {
                const int k = kq + e;
                bfr[gi][0][e] = (k < INP) ? (_Float16)wr[k] : (_Float16)0.0f;
            }
            const float* hr = Whh0 + gr * HID;
#pragma unroll
            for (int e = 0; e < 8; ++e) {
                bfr[gi][1][e] = (_Float16)hr[kq + e];
                bfr[gi][2][e] = (_Float16)hr[32 + kq + e];
            }
            bfr[gi][3] = bfr[gi][2];   // unused on this path
            bz[gi] = bih0[gr] + bhh0[gr];
        } else {
            const float* ir = Wih1 + gr * HID;
            const float* hr = Whh1 + gr * HID;
#pragma unroll
            for (int e = 0; e < 8; ++e) {
                bfr[gi][0][e] = (_Float16)ir[kq + e];
                bfr[gi][1][e] = (_Float16)ir[32 + kq + e];
                bfr[gi][2][e] = (_Float16)hr[kq + e];
                bfr[gi][3][e] = (_Float16)hr[32 + kq + e];
            }
            bz[gi] = bih1[gr] + bhh1[gr];
        }
    }

    // cell state: rows quad*4..+3 of unit u (fixed lane ownership across t)
    float cst[4] = {0.f, 0.f, 0.f, 0.f};

    // ---- x staging constants (threads 0..303 stage one element/iter) ----
    int srr = 0, sii = 0;
    const float* xsrc = nullptr;
    if (tid < ROWS * INP) {
        srr = tid / INP; sii = tid - srr * INP;
        xsrc = x + ((size_t)(b0 + srr) * T_STEPS) * INP + sii;
    }

    // ---- init LDS ----
    for (int e = tid; e < ROWS * XSTH; e += NTH) ((_Float16*)xf)[e] = (_Float16)0.f;
    for (int e = tid; e < ROWS * HSTH; e += NTH) {
        ((_Float16*)h1f)[e] = (_Float16)0.f;
        ((_Float16*)h2f)[e] = (_Float16)0.f;
    }
    __syncthreads();
    if (xsrc) xf[srr][sii] = (_Float16)xsrc[0];     // stage x(0)
    __syncthreads();

    for (int t = 0; t <= T_STEPS; ++t) {
        const bool act = (lay == 0) ? (t < T_STEPS) : (t >= 1);
        float hv[4];
        if (act) {
            floatx4 acc[4];
#pragma unroll
            for (int gi = 0; gi < 4; ++gi)
                acc[gi] = (floatx4){bz[gi], bz[gi], bz[gi], bz[gi]};
            if (lay == 0) {
                // A[m=lane&15][k=quad*8+e]
                const half8 ax = *(const half8*)&xf [l16][kq];
                const half8 a0 = *(const half8*)&h1f[l16][kq];
                const half8 a1 = *(const half8*)&h1f[l16][32 + kq];
#pragma unroll
                for (int gi = 0; gi < 4; ++gi) {
                    acc[gi] = __builtin_amdgcn_mfma_f32_16x16x32_f16(ax, bfr[gi][0], acc[gi], 0, 0, 0);
                    acc[gi] = __builtin_amdgcn_mfma_f32_16x16x32_f16(a0, bfr[gi][1], acc[gi], 0, 0, 0);
                    acc[gi] = __builtin_amdgcn_mfma_f32_16x16x32_f16(a1, bfr[gi][2], acc[gi], 0, 0, 0);
                }
            } else {
                const half8 p0 = *(const half8*)&h1f[l16][kq];
                const half8 p1 = *(const half8*)&h1f[l16][32 + kq];
                const half8 q0 = *(const half8*)&h2f[l16][kq];
                const half8 q1 = *(const half8*)&h2f[l16][32 + kq];
#pragma unroll
                for (int gi = 0; gi < 4; ++gi) {
                    acc[gi] = __builtin_amdgcn_mfma_f32_16x16x32_f16(p0, bfr[gi][0], acc[gi], 0, 0, 0);
                    acc[gi] = __builtin_amdgcn_mfma_f32_16x16x32_f16(p1, bfr[gi][1], acc[gi], 0, 0, 0);
                    acc[gi] = __builtin_amdgcn_mfma_f32_16x16x32_f16(q0, bfr[gi][2], acc[gi], 0, 0, 0);
                    acc[gi] = __builtin_amdgcn_mfma_f32_16x16x32_f16(q1, bfr[gi][3], acc[gi], 0, 0, 0);
                }
            }
            // activations entirely in the C-layout: lane owns 4 cells of unit u
#pragma unroll
            for (int rg = 0; rg < 4; ++rg) {
                const float ig = fast_sigmoid(acc[0][rg]);
                const float fg = fast_sigmoid(acc[1][rg]);
                const float gg = fast_tanh(acc[2][rg]);
                const float og = fast_sigmoid(acc[3][rg]);
                cst[rg] = fg * cst[rg] + ig * gg;
                hv[rg]  = og * fast_tanh(cst[rg]);
            }
        }
        __syncthreads();   // alpha: all A-frag reads of this iter done

        if (act) {
#pragma unroll
            for (int rg = 0; rg < 4; ++rg) {
                const int row = quad * 4 + rg;
                if (lay == 0) {
                    h1f[row][u] = (_Float16)hv[rg];          // h1(t)
                } else {
                    h2f[row][u] = (_Float16)hv[rg];          // h2(t-1)
                    if (t == T_STEPS) hout[row][u] = hv[rg]; // final h2, fp32
                }
            }
        }
        if (t + 1 < T_STEPS && xsrc)
            xf[srr][sii] = (_Float16)xsrc[(size_t)(t + 1) * INP];   // stage x(t+1)
        __syncthreads();   // beta: h/x updates visible for next iter
    }

    // ---- FC epilogue: out[b] = h2(T-1)[b,:] . Wfc + bfc ----
    if (tid < ROWS) {
        float a = bfc[0];
        const float* hr = hout[tid];
#pragma unroll
        for (int k = 0; k < HID; ++k)
            a = fmaf(hr[k], Wfc[k], a);
        out[b0 + tid] = a;
    }
}

extern "C" void kernel_launch(void* const* d_in, const int* in_sizes, int n_in,
                              void* d_out, int out_size, void* d_ws, size_t ws_size,
                              hipStream_t stream) {
    const float* x    = (const float*)d_in[0];
    const float* Wih0 = (const float*)d_in[1];
    const float* Whh0 = (const float*)d_in[2];
    const float* bih0 = (const float*)d_in[3];
    const float* bhh0 = (const float*)d_in[4];
    const float* Wih1 = (const float*)d_in[5];
    const float* Whh1 = (const float*)d_in[6];
    const float* bih1 = (const float*)d_in[7];
    const float* bhh1 = (const float*)d_in[8];
    const float* Wfc  = (const float*)d_in[9];
    const float* bfc  = (const float*)d_in[10];
    float* out = (float*)d_out;

    const int B = in_sizes[0] / (T_STEPS * INP);   // 4096
    const int grid = B / ROWS;                     // 256 workgroups, 1 per CU

    lstm2_mfma2_kernel<<<dim3(grid), dim3(NTH), 0, stream>>>(
        x, Wih0, Whh0, bih0, bhh0, Wih1, Whh1, bih1, bhh1, Wfc, bfc, out);
}

// Round 8
// 252.985 us; speedup vs baseline: 23.3518x; 1.1853x over previous
//
#include <hip/hip_runtime.h>
#include <math.h>

#define T_STEPS 168
#define INP     19
#define HID     64
#define ROWS    16
#define NTH     512
#define HSTH    72    // h row stride (f16): 144 B, 16B-aligned
#define XSTH    40    // x row stride (f16): 80 B

typedef _Float16 half8   __attribute__((ext_vector_type(8)));
typedef float    floatx4 __attribute__((ext_vector_type(4)));

__device__ __forceinline__ float fast_sigmoid(float x) {
    return __builtin_amdgcn_rcpf(1.0f + __expf(-x));
}
__device__ __forceinline__ float fast_tanh(float x) {
    return 1.0f - 2.0f * __builtin_amdgcn_rcpf(1.0f + __expf(2.0f * x));
}

// r7 structure (per-wave all-4-gates MFMA, activations in C-layout, c-state in
// regs) + two latency fixes:
//  1. x global load software-pipelined one iter ahead (register-held): the
//     scattered load no longer sits between barriers (r7: ~3600 cyc/iter with
//     all pipes <40% = latency-bound on that load's vmcnt drain).
//  2. xf/h1f/h2f double-buffered -> ONE barrier per iter instead of two.
// Buffer discipline at iter t:  rd xf[t&1], h1f[(t+1)&1], h2f[t&1]
//                               wr xf[(t+1)&1], h1f[t&1], h2f[(t+1)&1]
__global__ __launch_bounds__(NTH) __attribute__((amdgpu_waves_per_eu(2, 2)))
void lstm2_mfma3_kernel(const float* __restrict__ x,
                        const float* __restrict__ Wih0, const float* __restrict__ Whh0,
                        const float* __restrict__ bih0, const float* __restrict__ bhh0,
                        const float* __restrict__ Wih1, const float* __restrict__ Whh1,
                        const float* __restrict__ bih1, const float* __restrict__ bhh1,
                        const float* __restrict__ Wfc,  const float* __restrict__ bfc,
                        float* __restrict__ out)
{
    __shared__ __align__(16) _Float16 xf [2][ROWS][XSTH];   // cols 19.. stay 0
    __shared__ __align__(16) _Float16 h1f[2][ROWS][HSTH];
    __shared__ __align__(16) _Float16 h2f[2][ROWS][HSTH];
    __shared__ float hout[ROWS][HID];                       // fp32 h2(T-1) for FC

    const int tid  = threadIdx.x;
    const int b0   = blockIdx.x * ROWS;
    const int wv   = tid >> 6;
    const int lane = tid & 63;
    const int quad = lane >> 4;
    const int l16  = lane & 15;
    const int kq   = quad * 8;         // k-offset inside a 32-wide K-tile
    const int lay  = wv >> 2;          // 0: layer1(t), 1: layer2(t-1)
    const int uq   = wv & 3;           // unit quarter
    const int u    = uq * 16 + l16;    // my unit column

    // ---- B-fragments (weights, f16) + bias: loaded ONCE ----
    // B[k][n]: n = lane&15, k = quad*8 + e
    half8 bfr[4][4];
    float bz[4];
#pragma unroll
    for (int gi = 0; gi < 4; ++gi) {
        const int gr = gi * 64 + u;
        if (lay == 0) {
            const float* wr = Wih0 + gr * INP;
#pragma unroll
            for (int e = 0; e < 8; ++e) {
                const int k = kq + e;
                bfr[gi][0][e] = (k < INP) ? (_Float16)wr[k] : (_Float16)0.0f;
            }
            const float* hr = Whh0 + gr * HID;
#pragma unroll
            for (int e = 0; e < 8; ++e) {
                bfr[gi][1][e] = (_Float16)hr[kq + e];
                bfr[gi][2][e] = (_Float16)hr[32 + kq + e];
            }
            bfr[gi][3] = bfr[gi][2];   // unused on this path
            bz[gi] = bih0[gr] + bhh0[gr];
        } else {
            const float* ir = Wih1 + gr * HID;
            const float* hr = Whh1 + gr * HID;
#pragma unroll
            for (int e = 0; e < 8; ++e) {
                bfr[gi][0][e] = (_Float16)ir[kq + e];
                bfr[gi][1][e] = (_Float16)ir[32 + kq + e];
                bfr[gi][2][e] = (_Float16)hr[kq + e];
                bfr[gi][3][e] = (_Float16)hr[32 + kq + e];
            }
            bz[gi] = bih1[gr] + bhh1[gr];
        }
    }

    // cell state: rows quad*4..+3 of unit u
    float cst[4] = {0.f, 0.f, 0.f, 0.f};

    // ---- x staging constants (threads 0..303 stage one element/iter) ----
    int srr = 0, sii = 0;
    const float* xsrc = nullptr;
    if (tid < ROWS * INP) {
        srr = tid / INP; sii = tid - srr * INP;
        xsrc = x + ((size_t)(b0 + srr) * T_STEPS) * INP + sii;
    }

    // ---- init LDS (both buffers zero; pad cols stay zero forever) ----
    for (int e = tid; e < 2 * ROWS * XSTH; e += NTH) ((_Float16*)xf)[e] = (_Float16)0.f;
    for (int e = tid; e < 2 * ROWS * HSTH; e += NTH) {
        ((_Float16*)h1f)[e] = (_Float16)0.f;
        ((_Float16*)h2f)[e] = (_Float16)0.f;
    }
    __syncthreads();
    float xreg = 0.f;
    if (xsrc) {
        xf[0][srr][sii] = (_Float16)xsrc[0];   // stage x(0) directly
        xreg = xsrc[INP];                      // x(1) held in register
    }
    __syncthreads();

    for (int t = 0; t <= T_STEPS; ++t) {
        // ---- issue x(t+2) load FIRST: latency overlaps the whole compute ----
        float xnew = 0.f;
        if (xsrc) {
            const int tn = (t + 2 < T_STEPS) ? (t + 2) : (T_STEPS - 1);
            xnew = xsrc[(size_t)tn * INP];
        }
        // ---- stage x(t+1) from the register loaded last iter (no vm wait) ----
        if (xsrc && (t + 1) < T_STEPS)
            xf[(t + 1) & 1][srr][sii] = (_Float16)xreg;

        const bool act = (lay == 0) ? (t < T_STEPS) : (t >= 1);
        if (act) {
            floatx4 acc[4];
#pragma unroll
            for (int gi = 0; gi < 4; ++gi)
                acc[gi] = (floatx4){bz[gi], bz[gi], bz[gi], bz[gi]};
            if (lay == 0) {
                // A[m=lane&15][k=quad*8+e]
                const half8 ax = *(const half8*)&xf [t & 1][l16][kq];
                const half8 a0 = *(const half8*)&h1f[(t + 1) & 1][l16][kq];
                const half8 a1 = *(const half8*)&h1f[(t + 1) & 1][l16][32 + kq];
#pragma unroll
                for (int gi = 0; gi < 4; ++gi) {
                    acc[gi] = __builtin_amdgcn_mfma_f32_16x16x32_f16(ax, bfr[gi][0], acc[gi], 0, 0, 0);
                    acc[gi] = __builtin_amdgcn_mfma_f32_16x16x32_f16(a0, bfr[gi][1], acc[gi], 0, 0, 0);
                    acc[gi] = __builtin_amdgcn_mfma_f32_16x16x32_f16(a1, bfr[gi][2], acc[gi], 0, 0, 0);
                }
            } else {
                const half8 p0 = *(const half8*)&h1f[(t + 1) & 1][l16][kq];
                const half8 p1 = *(const half8*)&h1f[(t + 1) & 1][l16][32 + kq];
                const half8 q0 = *(const half8*)&h2f[t & 1][l16][kq];
                const half8 q1 = *(const half8*)&h2f[t & 1][l16][32 + kq];
#pragma unroll
                for (int gi = 0; gi < 4; ++gi) {
                    acc[gi] = __builtin_amdgcn_mfma_f32_16x16x32_f16(p0, bfr[gi][0], acc[gi], 0, 0, 0);
                    acc[gi] = __builtin_amdgcn_mfma_f32_16x16x32_f16(p1, bfr[gi][1], acc[gi], 0, 0, 0);
                    acc[gi] = __builtin_amdgcn_mfma_f32_16x16x32_f16(q0, bfr[gi][2], acc[gi], 0, 0, 0);
                    acc[gi] = __builtin_amdgcn_mfma_f32_16x16x32_f16(q1, bfr[gi][3], acc[gi], 0, 0, 0);
                }
            }
            // activations in C-layout: lane owns cells (row=quad*4+rg, u)
#pragma unroll
            for (int rg = 0; rg < 4; ++rg) {
                const float ig = fast_sigmoid(acc[0][rg]);
                const float fg = fast_sigmoid(acc[1][rg]);
                const float gg = fast_tanh(acc[2][rg]);
                const float og = fast_sigmoid(acc[3][rg]);
                cst[rg] = fg * cst[rg] + ig * gg;
                const float hv = og * fast_tanh(cst[rg]);
                const int row = quad * 4 + rg;
                if (lay == 0) {
                    h1f[t & 1][row][u] = (_Float16)hv;              // h1(t)
                } else {
                    h2f[(t + 1) & 1][row][u] = (_Float16)hv;        // h2(t-1)
                    if (t == T_STEPS) hout[row][u] = hv;            // fp32 for FC
                }
            }
        }
        xreg = xnew;       // vm wait lands here, after all compute
        __syncthreads();   // single barrier: iter-t writes visible to iter t+1
    }

    // ---- FC epilogue: out[b] = h2(T-1)[b,:] . Wfc + bfc ----
    if (tid < ROWS) {
        float a = bfc[0];
        const float* hr = hout[tid];
#pragma unroll
        for (int k = 0; k < HID; ++k)
            a = fmaf(hr[k], Wfc[k], a);
        out[b0 + tid] = a;
    }
}

extern "C" void kernel_launch(void* const* d_in, const int* in_sizes, int n_in,
                              void* d_out, int out_size, void* d_ws, size_t ws_size,
                              hipStream_t stream) {
    const float* x    = (const float*)d_in[0];
    const float* Wih0 = (const float*)d_in[1];
    const float* Whh0 = (const float*)d_in[2];
    const float* bih0 = (const float*)d_in[3];
    const float* bhh0 = (const float*)d_in[4];
    const float* Wih1 = (const float*)d_in[5];
    const float* Whh1 = (const float*)d_in[6];
    const float* bih1 = (const float*)d_in[7];
    const float* bhh1 = (const float*)d_in[8];
    const float* Wfc  = (const float*)d_in[9];
    const float* bfc  = (const float*)d_in[10];
    float* out = (float*)d_out;

    const int B = in_sizes[0] / (T_STEPS * INP);   // 4096
    const int grid = B / ROWS;                     // 256 workgroups, 1 per CU

    lstm2_mfma3_kernel<<<dim3(grid), dim3(NTH), 0, stream>>>(
        x, Wih0, Whh0, bih0, bhh0, Wih1, Whh1, bih1, bhh1, Wfc, bfc, out);
}